// Round 2
// baseline (439.622 us; speedup 1.0000x reference)
//
#include <hip/hip_runtime.h>
#include <hip/hip_bf16.h>

#define BATCH   256
#define NLAYERS 32
#define HID     1024
#define INTER   2816

typedef __attribute__((ext_vector_type(8))) short bf16x8;
typedef __attribute__((ext_vector_type(4))) float f32x4;
typedef __attribute__((ext_vector_type(4))) int   i32x4;

__device__ __forceinline__ ushort f2bf(float f) {
  __hip_bfloat16 b = __float2bfloat16(f);          // RNE; compiler can pair into v_cvt_pk_bf16_f32
  return *reinterpret_cast<ushort*>(&b);
}

__device__ __forceinline__ ushort f2bf_rne(float f) {  // for paths where exact RNE bit-twiddle is kept
  union { float f; unsigned u; } v; v.f = f;
  unsigned u = v.u;
  u += 0x7FFFu + ((u >> 16) & 1u);
  return (ushort)(u >> 16);
}

__device__ __forceinline__ void cvt_store4(ushort* dst, f32x4 a) {
  ushort4 o;
  o.x = f2bf(a[0]); o.y = f2bf(a[1]); o.z = f2bf(a[2]); o.w = f2bf(a[3]);
  *(ushort4*)dst = o;
}

// ---------------------------------------------------------------------------
// Kernel 1: act[layer][b][i] = silu(X Wg^T) * (X Wu^T), bf16 -> ws.
// BM=128, BN=32 (gate AND up for those 32 cols), BK=32, 256 threads = 4 waves
// as 2(M)x2(N); per wave 64 rows x 16 cols of gate and up (acc = 8 f32x4).
// LDS rows padded to 40 ushorts (80 B) -> ds_read_b128 is 2-way max (free).
// All global loads are lane-contiguous f32x4 (128 B/row-segment, coalesced).
// Grid ordered (layer, itile, mtile) so the mt=0/1 pair sharing a weight tile
// is adjacent in dispatch (L2/L3 serves the second read).
// ---------------------------------------------------------------------------
#define LDR 40   // padded row length in ushorts (32 data + 8 pad)

__global__ __launch_bounds__(256) void k_gateup(
    const float* __restrict__ h, const float* __restrict__ Wg,
    const float* __restrict__ Wu, ushort* __restrict__ act) {
  const int bid   = blockIdx.x;
  const int layer = bid / 176;          // 176 = (INTER/32)*2 mtiles... = 88*2
  const int rem   = bid % 176;
  const int it    = rem >> 1;
  const int mt    = rem & 1;
  const int i0    = it * 32;
  const int m0    = mt * 128;
  const int tid   = threadIdx.x;
  const int lane  = tid & 63;
  const int wave  = tid >> 6;
  const int wm    = wave >> 1;          // 0..1 : 64-row block
  const int wn    = wave & 1;           // 0..1 : 16-col block

  __shared__ ushort Xl[128 * LDR];      // 10240 B
  __shared__ ushort Gl[32 * LDR];       //  2560 B
  __shared__ ushort Ul[32 * LDR];       //  2560 B

  f32x4 ag[4] = {}, au[4] = {};

  // staging geometry: X = 1024 f32x4 granules (4/thread), G,U = 256 (1/thread)
  const float* xsrc[4]; int xdst[4];
#pragma unroll
  for (int r = 0; r < 4; ++r) {
    int g = tid + 256 * r;
    int row = g >> 3, u = g & 7;
    xsrc[r] = h + (size_t)(m0 + row) * (NLAYERS * HID) + (size_t)layer * HID + u * 4;
    xdst[r] = row * LDR + u * 4;
  }
  const int grow = tid >> 3, gu = tid & 7;
  const int gdst = grow * LDR + gu * 4;
  const float* gsrc = Wg + (size_t)layer * INTER * HID + (size_t)(i0 + grow) * HID + gu * 4;
  const float* usrc = Wu + (size_t)layer * INTER * HID + (size_t)(i0 + grow) * HID + gu * 4;

  f32x4 rx[4], rg, ru;
#pragma unroll
  for (int r = 0; r < 4; ++r) rx[r] = *(const f32x4*)xsrc[r];
  rg = *(const f32x4*)gsrc;
  ru = *(const f32x4*)usrc;

  const int NK = HID / 32;              // 32 steps
  for (int k = 0; k < NK; ++k) {
    __syncthreads();
#pragma unroll
    for (int r = 0; r < 4; ++r) cvt_store4(&Xl[xdst[r]], rx[r]);
    cvt_store4(&Gl[gdst], rg);
    cvt_store4(&Ul[gdst], ru);
    __syncthreads();

    if (k + 1 < NK) {
      int off = (k + 1) * 32;
#pragma unroll
      for (int r = 0; r < 4; ++r) rx[r] = *(const f32x4*)(xsrc[r] + off);
      rg = *(const f32x4*)(gsrc + off);
      ru = *(const f32x4*)(usrc + off);
    }

    const int kg = lane >> 4;           // 16B unit 0..3 = full K=32
    bf16x8 af[4];
#pragma unroll
    for (int m = 0; m < 4; ++m) {
      int row = wm * 64 + m * 16 + (lane & 15);
      af[m] = *(bf16x8*)&Xl[row * LDR + kg * 8];
    }
    const int brow = wn * 16 + (lane & 15);
    bf16x8 bg = *(bf16x8*)&Gl[brow * LDR + kg * 8];
    bf16x8 bu = *(bf16x8*)&Ul[brow * LDR + kg * 8];
#pragma unroll
    for (int m = 0; m < 4; ++m) {
      ag[m] = __builtin_amdgcn_mfma_f32_16x16x32_bf16(af[m], bg, ag[m], 0, 0, 0);
      au[m] = __builtin_amdgcn_mfma_f32_16x16x32_bf16(af[m], bu, au[m], 0, 0, 0);
    }
  }

  // epilogue: silu(gate)*up.  C/D map: col=lane&15, row=(lane>>4)*4+r
  const int c16 = lane & 15;
  const int r4  = (lane >> 4) * 4;
  const int i   = i0 + wn * 16 + c16;
#pragma unroll
  for (int m = 0; m < 4; ++m)
#pragma unroll
    for (int r = 0; r < 4; ++r) {
      float g = ag[m][r];
      float u = au[m][r];
      float a = (g / (1.f + __expf(-g))) * u;
      int b = m0 + wm * 64 + m * 16 + r4 + r;
      act[((size_t)layer * BATCH + b) * INTER + i] = f2bf_rne(a);
    }
}

// ---------------------------------------------------------------------------
// Kernel 2: out[b][layer][d] = act Wd^T.  UNCHANGED from R1 (measured at its
// roofline: ~68 us ~= (369 MB Wd + 32 MB out)/5.9 TB/s, act L3-resident).
// ---------------------------------------------------------------------------
#define BK 64

__device__ __forceinline__ void cvt_store8(ushort* dst, f32x4 a, f32x4 b) {
  bf16x8 o;
  o[0] = (short)f2bf_rne(a[0]); o[1] = (short)f2bf_rne(a[1]);
  o[2] = (short)f2bf_rne(a[2]); o[3] = (short)f2bf_rne(a[3]);
  o[4] = (short)f2bf_rne(b[0]); o[5] = (short)f2bf_rne(b[1]);
  o[6] = (short)f2bf_rne(b[2]); o[7] = (short)f2bf_rne(b[3]);
  *(bf16x8*)dst = o;
}

__global__ __launch_bounds__(512) void k_down(
    const ushort* __restrict__ act, const float* __restrict__ Wd,
    float* __restrict__ out) {
  const int bid   = blockIdx.x;
  const int layer = bid / (HID / 64);
  const int dtile = bid % (HID / 64);
  const int d0    = dtile * 64;
  const int tid   = threadIdx.x;
  const int lane  = tid & 63;
  const int wave  = tid >> 6;
  const int wm    = wave >> 1;
  const int wn    = wave & 1;

  __shared__ ushort lds[BATCH * BK + 64 * BK];       // 40 KiB
  ushort* Al = lds;
  ushort* Wl = lds + BATCH * BK;

  f32x4 acc[4][2] = {};

  int aldst[4];
  const ushort* asrc[4];
#pragma unroll
  for (int r = 0; r < 4; ++r) {
    int g = tid + 512 * r;
    int arow = g >> 3, akc = g & 7;
    aldst[r] = arow * BK + ((akc ^ (arow & 7)) << 3);
    asrc[r] = act + ((size_t)layer * BATCH + arow) * INTER + akc * 8;
  }
  const int wrow = tid >> 3, wkc = tid & 7;
  const int wldst = wrow * BK + ((wkc ^ (wrow & 7)) << 3);
  const float* wsrc = Wd + (size_t)layer * HID * INTER + (size_t)(d0 + wrow) * INTER + wkc * 8;

  i32x4 ra[4];
  f32x4 rw[2];

#pragma unroll
  for (int r = 0; r < 4; ++r) ra[r] = *(const i32x4*)asrc[r];
  rw[0] = *(const f32x4*)wsrc; rw[1] = *(const f32x4*)(wsrc + 4);

  const int NK = INTER / BK;   // 44
  for (int k = 0; k < NK; ++k) {
    __syncthreads();
#pragma unroll
    for (int r = 0; r < 4; ++r) *(i32x4*)&Al[aldst[r]] = ra[r];
    cvt_store8(&Wl[wldst], rw[0], rw[1]);
    __syncthreads();

    if (k + 1 < NK) {
      int off = (k + 1) * BK;
#pragma unroll
      for (int r = 0; r < 4; ++r) ra[r] = *(const i32x4*)(asrc[r] + off);
      rw[0] = *(const f32x4*)(wsrc + off); rw[1] = *(const f32x4*)(wsrc + off + 4);
    }

#pragma unroll
    for (int ks = 0; ks < 2; ++ks) {
      const int kg = ks * 4 + (lane >> 4);
      bf16x8 af[4];
#pragma unroll
      for (int m = 0; m < 4; ++m) {
        int row = wm * 64 + m * 16 + (lane & 15);
        af[m] = *(bf16x8*)&Al[row * BK + ((kg ^ (row & 7)) << 3)];
      }
#pragma unroll
      for (int n = 0; n < 2; ++n) {
        int row = wn * 32 + n * 16 + (lane & 15);
        bf16x8 bw = *(bf16x8*)&Wl[row * BK + ((kg ^ (row & 7)) << 3)];
#pragma unroll
        for (int m = 0; m < 4; ++m)
          acc[m][n] = __builtin_amdgcn_mfma_f32_16x16x32_bf16(af[m], bw, acc[m][n], 0, 0, 0);
      }
    }
  }

  const int c16 = lane & 15;
  const int r4  = (lane >> 4) * 4;
#pragma unroll
  for (int m = 0; m < 4; ++m)
#pragma unroll
    for (int n = 0; n < 2; ++n)
#pragma unroll
      for (int r = 0; r < 4; ++r) {
        int b = wm * 64 + m * 16 + r4 + r;
        int d = d0 + wn * 32 + n * 16 + c16;
        out[(size_t)b * (NLAYERS * HID) + (size_t)layer * HID + d] = acc[m][n][r];
      }
}

extern "C" void kernel_launch(void* const* d_in, const int* in_sizes, int n_in,
                              void* d_out, int out_size, void* d_ws, size_t ws_size,
                              hipStream_t stream) {
  const float* h  = (const float*)d_in[0];
  const float* Wg = (const float*)d_in[1];
  const float* Wu = (const float*)d_in[2];
  const float* Wd = (const float*)d_in[3];
  float* out  = (float*)d_out;
  ushort* act = (ushort*)d_ws;   // 32*256*2816*2 = 46.1 MB of scratch

  hipLaunchKernelGGL(k_gateup, dim3(NLAYERS * 176), dim3(256), 0, stream,
                     h, Wg, Wu, act);
  hipLaunchKernelGGL(k_down, dim3(NLAYERS * (HID / 64)), dim3(512), 0, stream,
                     act, Wd, out);
}